// Round 7
// baseline (1269.148 us; speedup 1.0000x reference)
//
#include <hip/hip_runtime.h>
#include <hip/hip_bf16.h>
#include <cstdint>

#define NB 64        // batch
#define ND 64        // DIM
#define NH 8         // heads
#define NTOK 226
#define NSB 128      // 2*B (both streams batched)
#define NROWS (NSB*NTOK)   // 28928

#define XTP 232      // xt pitch (u16): 464 B rows, 16B-aligned, uniform-bank reads
#define PWP 40       // per-wave staging pitch (u16): quad-halves split banks

typedef __attribute__((ext_vector_type(8))) short bfrag8;
typedef __attribute__((ext_vector_type(4))) float ffrag4;

// RNE bf16 (bit-exact vs __float2bfloat16 for finite values; 3 VALU ops)
__device__ __forceinline__ unsigned short f2b(float f) {
  uint32_t u; __builtin_memcpy(&u, &f, 4);
  u += 0x7fff + ((u >> 16) & 1);
  return (unsigned short)(u >> 16);
}

// ---- fusion-matrix diagonal: sdfm[b][d] = sqrt(sigmoid(x @ fmg_w[:,65d])) ----
__global__ void k_dfm(const float* __restrict__ hsi, const float* __restrict__ lidar,
                      const float* __restrict__ fmg_w, float* __restrict__ sdfm) {
  __shared__ float xc[128];
  int b = blockIdx.x, t = threadIdx.x;
  const float* src = (t < 64) ? hsi : lidar;
  int d = t & 63;
  const float* p = src + ((size_t)b * 64 + d) * 225;
  float s = 0.f;
  for (int i = 0; i < 225; ++i) s += p[i];
  xc[t] = s * (1.0f / 225.0f);
  __syncthreads();
  if (t < 64) {
    float acc = 0.f;
    const float* w = fmg_w + t * 65;       // column 65*t of [128,4096]
    for (int c = 0; c < 128; ++c) acc += xc[c] * w[c * 4096];
    float sg = 1.0f / (1.0f + expf(-acc));
    sdfm[b * 64 + t] = sqrtf(sg);
  }
}

// ---- build X[2B,226,64] (+ pos) and Xn = LN1_0(X); one wave per row ----
__global__ void k_build(const float* __restrict__ hsi,
                        const float* __restrict__ cls_h, const float* __restrict__ cls_l,
                        const float* __restrict__ pos_h, const float* __restrict__ pos_l,
                        const float* __restrict__ g, const float* __restrict__ bb,
                        float* __restrict__ X, uint16_t* __restrict__ Xn) {
  int r = blockIdx.x;                 // sb*226 + n
  int sb = r / NTOK, n = r - sb * NTOK;
  int s = sb >> 6, b = sb & 63;
  int d = threadIdx.x;                // 64 threads = 1 wave
  float v;
  if (n == 0) v = s ? cls_l[d] : cls_h[d];
  else        v = hsi[((size_t)b * 64 + d) * 225 + (n - 1)];
  v += (s ? pos_l : pos_h)[n * ND + d];
  X[(size_t)r * ND + d] = v;
  float sm = v, sq = v * v;
  #pragma unroll
  for (int o = 32; o; o >>= 1) { sm += __shfl_xor(sm, o); sq += __shfl_xor(sq, o); }
  float m = sm * (1.f / 64.f);
  float rs = rsqrtf(sq * (1.f / 64.f) - m * m + 1e-5f);
  Xn[(size_t)r * ND + d] = f2b((v - m) * rs * g[d] + bb[d]);
}

// ---- FF weight convert to bf16 [col][k] layouts ----
__global__ __launch_bounds__(256) void k_wconv2(
    const float* __restrict__ ff_w1, const float* __restrict__ ff_w2,
    uint16_t* __restrict__ W1, uint16_t* __restrict__ W2) {
  int i = blockIdx.x * 256 + threadIdx.x;   // 131072
  if (i < 65536) {
    int ly = i >> 14, rem = i & 16383, n = rem >> 6, k = rem & 63;
    W1[i] = f2b(ff_w1[((size_t)ly * 64 + k) * 256 + n]);
  } else {
    int j = i - 65536;
    int ly = j >> 14, rem = j & 16383, n = rem >> 8, k = rem & 255;
    W2[j] = f2b(ff_w2[((size_t)ly * 256 + k) * 64 + n]);
  }
}

// ---- Gt[ly][h][n][k] = (Wv_h · Wo_h)^T entries: fused V->proj weight ----
__global__ __launch_bounds__(256) void k_gconv(const float* __restrict__ qkv_w,
    const float* __restrict__ out_w, uint16_t* __restrict__ Gt) {
  int idx = blockIdx.x * 256 + threadIdx.x;   // 131072
  int ly = idx >> 15, h = (idx >> 12) & 7, d = (idx >> 6) & 63, n = idx & 63;
  const float* qp = qkv_w + ((size_t)(ly * 64 + d)) * 1536 + 1024 + h * 64;
  const float* op = out_w + ((size_t)(ly * 512 + h * 64)) * 64 + n;
  float acc = 0.f;
  for (int dh = 0; dh < 64; ++dh) acc += qp[dh] * op[(size_t)dh * 64];
  Gt[(((size_t)(ly * 8 + h) * 64 + n) << 6) + d] = f2b(acc);
}

// ---- Mt[ly][b][h][64][64] = Wq_h diag(dfm_b/8) Wq_h^T (symmetric) ----
// One wave per (ly,b,h): stage scaled Wq rows in swizzled LDS, self-product MFMA.
__global__ void k_mconv(const float* __restrict__ qkv_w,
    const float* __restrict__ sdfm, uint16_t* __restrict__ Mt) {
  __shared__ __align__(16) uint16_t ws[64 * 64];   // 8 KB
  int bx = blockIdx.x;                       // (ly, b, h)
  int ly = bx >> 9, b = (bx >> 3) & 63, h = bx & 7;
  int t = threadIdx.x;                       // 64 threads = 1 wave
  float sf = sdfm[b * 64 + t] * 0.35355339059327373f;   // sqrt(1/8)
  for (int k = 0; k < 64; ++k) {
    float wv = qkv_w[((size_t)(ly * 64 + k)) * 1536 + h * 64 + t];
    ws[k * 64 + (((t >> 3) ^ (k & 7)) << 3) + (t & 7)] = f2b(wv * sf);
  }
  __syncthreads();
  int quad = t >> 4, c = t & 15;
  uint16_t* out = Mt + ((size_t)bx << 12);
  for (int it = 0; it < 4; ++it) {
    int ra = it * 16 + c, sa = ra & 7;
    bfrag8 a0 = *(const bfrag8*)(ws + ra * 64 + ((quad ^ sa) << 3));
    bfrag8 a1 = *(const bfrag8*)(ws + ra * 64 + (((quad + 4) ^ sa) << 3));
    for (int jt = 0; jt < 4; ++jt) {
      int rb = jt * 16 + c, sk = rb & 7;
      bfrag8 b0 = *(const bfrag8*)(ws + rb * 64 + ((quad ^ sk) << 3));
      bfrag8 b1 = *(const bfrag8*)(ws + rb * 64 + (((quad + 4) ^ sk) << 3));
      ffrag4 z = {0.f, 0.f, 0.f, 0.f};
      z = __builtin_amdgcn_mfma_f32_16x16x32_bf16(a0, b0, z, 0, 0, 0);
      z = __builtin_amdgcn_mfma_f32_16x16x32_bf16(a1, b1, z, 0, 0, 0);
      #pragma unroll
      for (int r = 0; r < 4; ++r)
        out[(it * 16 + quad * 4 + r) * 64 + jt * 16 + c] = f2b(z[r]);
    }
  }
}

// ---- megakernel: S=Xn·M·Xn^T, softmax, O=Sum_h (E·Xn)·G_h, +bias+residual+LN2 ----
// Grid 512 = (sb, quarter). 4 waves, 1 i-tile each. One __syncthreads total.
__global__ __launch_bounds__(256) void k_mega(const uint16_t* __restrict__ Xn,
    const uint16_t* __restrict__ Mt,    // layer base: [64 b][8 h][64][64]
    const uint16_t* __restrict__ Gt,    // layer base: [8 h][64][64]
    const float* __restrict__ bo, float* __restrict__ X,
    const float* __restrict__ g2, const float* __restrict__ bb2,
    uint16_t* __restrict__ Xn2) {
  __shared__ __align__(16) uint16_t xt[64 * XTP];   // 29696 B: Xn^T
  __shared__ __align__(16) uint16_t pwb[4][16 * PWP]; // 5120 B: per-wave staging
  int bx = blockIdx.x, sb = bx >> 2, qq = bx & 3;
  int t = threadIdx.x, w = t >> 6, l = t & 63, quad = l >> 4, c = l & 15;
  const uint16_t* Xb = Xn + (size_t)sb * NTOK * ND;

  // stage xt = Xn^T (one-time; conflicts amortized)
  for (int idx = t; idx < NTOK * 32; idx += 256) {
    int j = idx >> 5, d2 = (idx & 31) << 1;
    uint32_t v = *(const uint32_t*)(Xb + j * 64 + d2);
    xt[d2 * XTP + j]       = (uint16_t)v;
    xt[(d2 + 1) * XTP + j] = (uint16_t)(v >> 16);
  }
  // zero pad cols 226..231
  for (int idx = t; idx < 64 * 3; idx += 256) {
    int d = idx / 3, cc = 226 + 2 * (idx % 3);
    *(uint32_t*)(xt + d * XTP + cc) = 0;
  }
  __syncthreads();

  int it = qq * 4 + w;
  if (it <= 14) {
    int i0 = it * 16;
    int ric = i0 + c; if (ric > 225) ric = 225;
    bfrag8 aXg0 = *(const bfrag8*)(Xb + (size_t)ric * 64 + quad * 8);
    bfrag8 aXg1 = *(const bfrag8*)(Xb + (size_t)ric * 64 + 32 + quad * 8);
    uint16_t* pw = &pwb[w][0];
    ffrag4 Oacc[4];
    #pragma unroll
    for (int dt = 0; dt < 4; ++dt) Oacc[dt] = (ffrag4){0.f, 0.f, 0.f, 0.f};
    const uint16_t* Mb = Mt + ((size_t)(sb & 63) << 15);   // *8*4096

    for (int h = 0; h < 8; ++h) {
      const uint16_t* Mh = Mb + ((size_t)h << 12);
      // T = Xn_strip · M  (C-layout)
      ffrag4 tacc[4];
      #pragma unroll
      for (int dt = 0; dt < 4; ++dt) {
        bfrag8 b0 = *(const bfrag8*)(Mh + (dt * 16 + c) * 64 + quad * 8);
        bfrag8 b1 = *(const bfrag8*)(Mh + (dt * 16 + c) * 64 + 32 + quad * 8);
        ffrag4 z = {0.f, 0.f, 0.f, 0.f};
        z = __builtin_amdgcn_mfma_f32_16x16x32_bf16(aXg0, b0, z, 0, 0, 0);
        z = __builtin_amdgcn_mfma_f32_16x16x32_bf16(aXg1, b1, z, 0, 0, 0);
        tacc[dt] = z;
      }
      // T -> A-layout frags via per-wave LDS halves
      bfrag8 aT0, aT1;
      #pragma unroll
      for (int half = 0; half < 2; ++half) {
        #pragma unroll
        for (int d2 = 0; d2 < 2; ++d2)
          #pragma unroll
          for (int r = 0; r < 4; ++r)
            pw[(quad * 4 + r) * PWP + d2 * 16 + c] = f2b(tacc[half * 2 + d2][r]);
        bfrag8 v = *(const bfrag8*)(pw + c * PWP + quad * 8);
        if (half == 0) aT0 = v; else aT1 = v;
      }
      // S strip = T · Xn^T  (B-frags: global Xn rows, [n=j][k] layout)
      ffrag4 sacc[15];
      #pragma unroll
      for (int jt = 0; jt < 15; ++jt) {
        int rj = jt * 16 + c; if (rj > 225) rj = 225;
        bfrag8 b0 = *(const bfrag8*)(Xb + (size_t)rj * 64 + quad * 8);
        bfrag8 b1 = *(const bfrag8*)(Xb + (size_t)rj * 64 + 32 + quad * 8);
        ffrag4 z = {0.f, 0.f, 0.f, 0.f};
        z = __builtin_amdgcn_mfma_f32_16x16x32_bf16(aT0, b0, z, 0, 0, 0);
        z = __builtin_amdgcn_mfma_f32_16x16x32_bf16(aT1, b1, z, 0, 0, 0);
        sacc[jt] = z;
      }
      // softmax (raw E kept; 1/l deferred)
      float rinv[4];
      #pragma unroll
      for (int r = 0; r < 4; ++r) {
        float m = -1e30f;
        #pragma unroll
        for (int jt = 0; jt < 15; ++jt) m = fmaxf(m, sacc[jt][r]);
        #pragma unroll
        for (int o = 8; o; o >>= 1) m = fmaxf(m, __shfl_xor(m, o));
        float s = 0.f;
        #pragma unroll
        for (int jt = 0; jt < 15; ++jt) {
          float p = __expf(sacc[jt][r] - m);
          if (jt == 14 && c >= 2) p = 0.f;   // j = 224+c >= 226 (dup rows) masked
          sacc[jt][r] = p;
          s += p;
        }
        #pragma unroll
        for (int o = 8; o; o >>= 1) s += __shfl_xor(s, o);
        rinv[r] = 1.f / s;
      }
      // U = E · Xn  (A: E chunks via pw; B: xt rows)
      ffrag4 uacc[4];
      #pragma unroll
      for (int dt = 0; dt < 4; ++dt) uacc[dt] = (ffrag4){0.f, 0.f, 0.f, 0.f};
      #pragma unroll
      for (int jc = 0; jc < 8; ++jc) {
        #pragma unroll
        for (int r = 0; r < 4; ++r) {
          int row = quad * 4 + r;
          pw[row * PWP + c] = f2b(sacc[2 * jc][r]);
          uint16_t hi = 0;
          if (jc < 7) hi = f2b(sacc[2 * jc + 1][r]);
          pw[row * PWP + 16 + c] = hi;
        }
        bfrag8 pa = *(const bfrag8*)(pw + c * PWP + quad * 8);
        int jb = (jc < 7) ? (jc * 32 + quad * 8) : 224;   // tail: dup quad0, E=0 above k>=2
        #pragma unroll
        for (int dt = 0; dt < 4; ++dt) {
          bfrag8 vb = *(const bfrag8*)(xt + (dt * 16 + c) * XTP + jb);
          uacc[dt] = __builtin_amdgcn_mfma_f32_16x16x32_bf16(pa, vb, uacc[dt], 0, 0, 0);
        }
      }
      // Oacc += (U*rinv) · G_h   (A: U halves via pw; B: Gt rows)
      const uint16_t* Gh = Gt + ((size_t)h << 12);
      #pragma unroll
      for (int half = 0; half < 2; ++half) {
        #pragma unroll
        for (int d2 = 0; d2 < 2; ++d2)
          #pragma unroll
          for (int r = 0; r < 4; ++r)
            pw[(quad * 4 + r) * PWP + d2 * 16 + c] = f2b(uacc[half * 2 + d2][r] * rinv[r]);
        bfrag8 aU = *(const bfrag8*)(pw + c * PWP + quad * 8);
        #pragma unroll
        for (int dt = 0; dt < 4; ++dt) {
          bfrag8 gb = *(const bfrag8*)(Gh + (dt * 16 + c) * 64 + half * 32 + quad * 8);
          Oacc[dt] = __builtin_amdgcn_mfma_f32_16x16x32_bf16(aU, gb, Oacc[dt], 0, 0, 0);
        }
      }
    }  // heads

    // epilogue: bias + residual + LN2 emission
    float xv[4][4];
    #pragma unroll
    for (int dt = 0; dt < 4; ++dt) {
      float bv = bo[dt * 16 + c];
      #pragma unroll
      for (int r = 0; r < 4; ++r) {
        int i = i0 + quad * 4 + r;
        float v = 0.f;
        if (i < NTOK) {
          size_t idx = ((size_t)sb * NTOK + i) * 64 + dt * 16 + c;
          v = X[idx] + Oacc[dt][r] + bv;
          X[idx] = v;
        }
        xv[dt][r] = v;
      }
    }
    #pragma unroll
    for (int r = 0; r < 4; ++r) {
      int i = i0 + quad * 4 + r;
      float s = xv[0][r] + xv[1][r] + xv[2][r] + xv[3][r];
      float q = xv[0][r]*xv[0][r] + xv[1][r]*xv[1][r] + xv[2][r]*xv[2][r] + xv[3][r]*xv[3][r];
      #pragma unroll
      for (int o = 8; o; o >>= 1) { s += __shfl_xor(s, o); q += __shfl_xor(q, o); }
      float m = s * (1.f / 64.f);
      float rs = rsqrtf(q * (1.f / 64.f) - m * m + 1e-5f);
      if (i < NTOK) {
        #pragma unroll
        for (int dt = 0; dt < 4; ++dt) {
          int n = dt * 16 + c;
          Xn2[((size_t)sb * NTOK + i) * 64 + n] = f2b((xv[dt][r] - m) * rs * g2[n] + bb2[n]);
        }
      }
    }
  }
}

// ---- MFMA FF (A-frags from global Xn2) + residual + next-layer LN1 emission ----
__global__ __launch_bounds__(256) void k_ff(float* __restrict__ X,
    const uint16_t* __restrict__ Xn2,
    const uint16_t* __restrict__ W1t,   // [256][64] bf16
    const float* __restrict__ b1,
    const uint16_t* __restrict__ W2t,   // [64][256] bf16
    const float* __restrict__ b2,
    const float* __restrict__ gn, const float* __restrict__ bbn,
    uint16_t* __restrict__ XnOut) {
  __shared__ __align__(16) uint16_t ha[4][16 * 264];   // 33792 B, per-wave h-tile
  int t = threadIdx.x, w = t >> 6, l = t & 63;
  int quad = l >> 4, c = l & 15;
  int r0 = blockIdx.x * 64;
  const uint16_t* xrow = Xn2 + (size_t)(r0 + w * 16 + c) * 64;
  bfrag8 a0 = *(const bfrag8*)(xrow + quad * 8);
  bfrag8 a1 = *(const bfrag8*)(xrow + 32 + quad * 8);
  ffrag4 acc[16];
  #pragma unroll
  for (int jt = 0; jt < 16; ++jt) {
    bfrag8 b0  = *(const bfrag8*)(W1t + (size_t)(jt * 16 + c) * 64 + quad * 8);
    bfrag8 b1f = *(const bfrag8*)(W1t + (size_t)(jt * 16 + c) * 64 + 32 + quad * 8);
    ffrag4 z = {0.f, 0.f, 0.f, 0.f};
    z = __builtin_amdgcn_mfma_f32_16x16x32_bf16(a0, b0, z, 0, 0, 0);
    z = __builtin_amdgcn_mfma_f32_16x16x32_bf16(a1, b1f, z, 0, 0, 0);
    acc[jt] = z;
  }
  uint16_t* haw = &ha[w][0];
  #pragma unroll
  for (int jt = 0; jt < 16; ++jt) {
    float bv = b1[jt * 16 + c];
    #pragma unroll
    for (int r = 0; r < 4; ++r) {
      float z = acc[jt][r] + bv;
      float hg = 0.5f * z * (1.f + erff(z * 0.7071067811865476f));
      haw[(quad * 4 + r) * 264 + jt * 16 + c] = f2b(hg);
    }
  }
  __syncthreads();
  ffrag4 o2[4];
  #pragma unroll
  for (int jt = 0; jt < 4; ++jt) o2[jt] = (ffrag4){0.f, 0.f, 0.f, 0.f};
  #pragma unroll
  for (int kc = 0; kc < 8; ++kc) {
    bfrag8 pa = *(const bfrag8*)(haw + c * 264 + kc * 32 + quad * 8);
    #pragma unroll
    for (int jt = 0; jt < 4; ++jt) {
      bfrag8 vb = *(const bfrag8*)(W2t + (size_t)(jt * 16 + c) * 256 + kc * 32 + quad * 8);
      o2[jt] = __builtin_amdgcn_mfma_f32_16x16x32_bf16(pa, vb, o2[jt], 0, 0, 0);
    }
  }
  float xv[4][4];
  #pragma unroll
  for (int jt = 0; jt < 4; ++jt) {
    float bv = b2[jt * 16 + c];
    #pragma unroll
    for (int r = 0; r < 4; ++r) {
      int il = w * 16 + quad * 4 + r;
      size_t idx = (size_t)(r0 + il) * 64 + jt * 16 + c;
      float v = X[idx] + o2[jt][r] + bv;
      X[idx] = v;
      xv[jt][r] = v;
    }
  }
  #pragma unroll
  for (int r = 0; r < 4; ++r) {
    float s = xv[0][r] + xv[1][r] + xv[2][r] + xv[3][r];
    float q = xv[0][r]*xv[0][r] + xv[1][r]*xv[1][r] + xv[2][r]*xv[2][r] + xv[3][r]*xv[3][r];
    #pragma unroll
    for (int o = 8; o; o >>= 1) { s += __shfl_xor(s, o); q += __shfl_xor(q, o); }
    float m = s * (1.f / 64.f);
    float rs = rsqrtf(q * (1.f / 64.f) - m * m + 1e-5f);
    int il = w * 16 + quad * 4 + r;
    #pragma unroll
    for (int jt = 0; jt < 4; ++jt) {
      int n = jt * 16 + c;
      XnOut[(size_t)(r0 + il) * 64 + n] = f2b((xv[jt][r] - m) * rs * gn[n] + bbn[n]);
    }
  }
}

// ---- swap cls tokens between streams; refresh Xn (LN1 layer0) for those rows ----
__global__ void k_xchg(float* __restrict__ X, uint16_t* __restrict__ Xn,
                       const float* __restrict__ g, const float* __restrict__ bb) {
  int b = blockIdx.x, d = threadIdx.x;   // 64 blocks x 64 threads (1 wave)
  size_t i0 = (size_t)(b * NTOK) * ND + d;
  size_t i1 = (size_t)((64 + b) * NTOK) * ND + d;
  float a = X[i0], cc = X[i1];
  X[i0] = cc; X[i1] = a;
  float s0 = cc, q0 = cc * cc, s1 = a, q1 = a * a;
  #pragma unroll
  for (int o = 32; o; o >>= 1) {
    s0 += __shfl_xor(s0, o); q0 += __shfl_xor(q0, o);
    s1 += __shfl_xor(s1, o); q1 += __shfl_xor(q1, o);
  }
  float m0 = s0 * (1.f / 64.f), rs0 = rsqrtf(q0 * (1.f / 64.f) - m0 * m0 + 1e-5f);
  float m1 = s1 * (1.f / 64.f), rs1 = rsqrtf(q1 * (1.f / 64.f) - m1 * m1 + 1e-5f);
  Xn[i0] = f2b((cc - m0) * rs0 * g[d] + bb[d]);
  Xn[i1] = f2b((a - m1) * rs1 * g[d] + bb[d]);
}

// ---- final: out = h_cls + l_cls ----
__global__ void k_out(const float* __restrict__ X, float* __restrict__ out) {
  int i = blockIdx.x * 64 + threadIdx.x;
  int b = i >> 6, d = i & 63;
  out[i] = X[(size_t)b * NTOK * ND + d] + X[(size_t)(64 + b) * NTOK * ND + d];
}

extern "C" void kernel_launch(void* const* d_in, const int* in_sizes, int n_in,
                              void* d_out, int out_size, void* d_ws, size_t ws_size,
                              hipStream_t stream) {
  const float* hsi   = (const float*)d_in[0];
  const float* lidar = (const float*)d_in[1];
  const float* cls_h = (const float*)d_in[2];
  const float* cls_l = (const float*)d_in[3];
  const float* pos_h = (const float*)d_in[4];
  const float* pos_l = (const float*)d_in[5];
  const float* fmg_w = (const float*)d_in[6];
  const float* ln1_g = (const float*)d_in[7];
  const float* ln1_b = (const float*)d_in[8];
  const float* qkv_w = (const float*)d_in[9];
  const float* out_w = (const float*)d_in[10];
  const float* out_b = (const float*)d_in[11];
  const float* ln2_g = (const float*)d_in[12];
  const float* ln2_b = (const float*)d_in[13];
  const float* ff_w1 = (const float*)d_in[14];
  const float* ff_b1 = (const float*)d_in[15];
  const float* ff_w2 = (const float*)d_in[16];
  const float* ff_b2 = (const float*)d_in[17];

  char* ws = (char*)d_ws;
  float*    X    = (float*)ws;                       // 7,405,568 B
  float*    sdfm = (float*)(ws + 7405568);           // 16,384 B
  uint16_t* Xn   = (uint16_t*)(ws + 7421952);        // 3,702,784 B
  uint16_t* Xn2  = (uint16_t*)(ws + 11124736);       // 3,702,784 B
  uint16_t* Mt   = (uint16_t*)(ws + 14827520);       // 16,777,216 B
  uint16_t* Gt   = (uint16_t*)(ws + 31604736);       // 262,144 B
  uint16_t* W1   = (uint16_t*)(ws + 31866880);       // 131,072 B
  uint16_t* W2   = (uint16_t*)(ws + 31997952);       // 131,072 B -> end 32,129,024

  k_wconv2<<<512, 256, 0, stream>>>(ff_w1, ff_w2, W1, W2);
  k_gconv<<<512, 256, 0, stream>>>(qkv_w, out_w, Gt);
  k_dfm<<<NB, 128, 0, stream>>>(hsi, lidar, fmg_w, sdfm);
  k_mconv<<<2048, 64, 0, stream>>>(qkv_w, sdfm, Mt);
  k_build<<<NROWS, 64, 0, stream>>>(hsi, cls_h, cls_l, pos_h, pos_l,
                                    ln1_g, ln1_b, X, Xn);
  for (int pass = 0; pass < 2; ++pass) {
    for (int ly = 0; ly < 4; ++ly) {
      int nx = (ly + 1) & 3;   // next layer's LN1 params (harmless on final layer)
      k_mega<<<512, 256, 0, stream>>>(Xn, Mt + (size_t)ly * 2097152,
                                      Gt + (size_t)ly * 32768, out_b + ly * ND,
                                      X, ln2_g + ly * ND, ln2_b + ly * ND, Xn2);
      k_ff<<<452, 256, 0, stream>>>(X, Xn2,
                                    W1 + (size_t)ly * 16384, ff_b1 + ly * 256,
                                    W2 + (size_t)ly * 16384, ff_b2 + ly * ND,
                                    ln1_g + nx * ND, ln1_b + nx * ND, Xn);
    }
    if (pass == 0) k_xchg<<<64, 64, 0, stream>>>(X, Xn, ln1_g, ln1_b);
  }
  k_out<<<64, 64, 0, stream>>>(X, (float*)d_out);
}

// Round 8
// 1218.277 us; speedup vs baseline: 1.0418x; 1.0418x over previous
//
#include <hip/hip_runtime.h>
#include <hip/hip_bf16.h>
#include <cstdint>

#define NB 64        // batch
#define ND 64        // DIM
#define NH 8         // heads
#define NTOK 226
#define NSB 128      // 2*B (both streams batched)
#define NROWS (NSB*NTOK)   // 28928

#define VTP 232      // vt (Xn^T) pitch in u16: mult of 8 (16B align), uniform b128 banks
#define PWP 72       // per-wave roundtrip pitch in u16 (16 rows x 64 cols max)

typedef __attribute__((ext_vector_type(8))) short bfrag8;
typedef __attribute__((ext_vector_type(4))) float ffrag4;

// RNE bf16 (bit-exact vs __float2bfloat16 for finite values; 3 VALU ops)
__device__ __forceinline__ unsigned short f2b(float f) {
  uint32_t u; __builtin_memcpy(&u, &f, 4);
  u += 0x7fff + ((u >> 16) & 1);
  return (unsigned short)(u >> 16);
}

// ---- fusion-matrix diagonal: sdfm[b][d] = sqrt(sigmoid(x @ fmg_w[:,65d])) ----
__global__ void k_dfm(const float* __restrict__ hsi, const float* __restrict__ lidar,
                      const float* __restrict__ fmg_w, float* __restrict__ sdfm) {
  __shared__ float xc[128];
  int b = blockIdx.x, t = threadIdx.x;
  const float* src = (t < 64) ? hsi : lidar;
  int d = t & 63;
  const float* p = src + ((size_t)b * 64 + d) * 225;
  float s = 0.f;
  for (int i = 0; i < 225; ++i) s += p[i];
  xc[t] = s * (1.0f / 225.0f);
  __syncthreads();
  if (t < 64) {
    float acc = 0.f;
    const float* w = fmg_w + t * 65;       // column 65*t of [128,4096]
    for (int c = 0; c < 128; ++c) acc += xc[c] * w[c * 4096];
    float sg = 1.0f / (1.0f + expf(-acc));
    sdfm[b * 64 + t] = sqrtf(sg);
  }
}

// ---- build X[2B,226,64] (+ pos) and Xn = LN1_0(X); one wave per row ----
__global__ void k_build(const float* __restrict__ hsi,
                        const float* __restrict__ cls_h, const float* __restrict__ cls_l,
                        const float* __restrict__ pos_h, const float* __restrict__ pos_l,
                        const float* __restrict__ g, const float* __restrict__ bb,
                        float* __restrict__ X, uint16_t* __restrict__ Xn) {
  int r = blockIdx.x;                 // sb*226 + n
  int sb = r / NTOK, n = r - sb * NTOK;
  int s = sb >> 6, b = sb & 63;
  int d = threadIdx.x;                // 64 threads = 1 wave
  float v;
  if (n == 0) v = s ? cls_l[d] : cls_h[d];
  else        v = hsi[((size_t)b * 64 + d) * 225 + (n - 1)];
  v += (s ? pos_l : pos_h)[n * ND + d];
  X[(size_t)r * ND + d] = v;
  float sm = v, sq = v * v;
  #pragma unroll
  for (int o = 32; o; o >>= 1) { sm += __shfl_xor(sm, o); sq += __shfl_xor(sq, o); }
  float m = sm * (1.f / 64.f);
  float rs = rsqrtf(sq * (1.f / 64.f) - m * m + 1e-5f);
  Xn[(size_t)r * ND + d] = f2b((v - m) * rs * g[d] + bb[d]);
}

// ---- FF weight convert to bf16 [col][k] layouts ----
__global__ __launch_bounds__(256) void k_wconv2(
    const float* __restrict__ ff_w1, const float* __restrict__ ff_w2,
    uint16_t* __restrict__ W1, uint16_t* __restrict__ W2) {
  int i = blockIdx.x * 256 + threadIdx.x;   // 131072
  if (i < 65536) {
    int ly = i >> 14, rem = i & 16383, n = rem >> 6, k = rem & 63;
    W1[i] = f2b(ff_w1[((size_t)ly * 64 + k) * 256 + n]);
  } else {
    int j = i - 65536;
    int ly = j >> 14, rem = j & 16383, n = rem >> 8, k = rem & 255;
    W2[j] = f2b(ff_w2[((size_t)ly * 256 + k) * 64 + n]);
  }
}

// ---- Gp[ly][n][h*64+d] = (Wv_h · Wo_h)[d][n]: fused V->proj weight, [n][k] ----
__global__ __launch_bounds__(256) void k_gconv(const float* __restrict__ qkv_w,
    const float* __restrict__ out_w, uint16_t* __restrict__ Gp) {
  int idx = blockIdx.x * 256 + threadIdx.x;   // 131072
  int ly = idx >> 15, h = (idx >> 12) & 7, d = (idx >> 6) & 63, n = idx & 63;
  const float* qp = qkv_w + ((size_t)(ly * 64 + d)) * 1536 + 1024 + h * 64;
  const float* op = out_w + ((size_t)(ly * 512 + h * 64)) * 64 + n;
  float acc = 0.f;
  for (int dh = 0; dh < 64; ++dh) acc += qp[dh] * op[(size_t)dh * 64];
  Gp[(size_t)(ly * 64 + n) * 512 + h * 64 + d] = f2b(acc);
}

// ---- Mt[ly][b][h][64][64] = Wq_h diag(dfm_b/8) Wq_h^T (symmetric) ----
__global__ void k_mconv(const float* __restrict__ qkv_w,
    const float* __restrict__ sdfm, uint16_t* __restrict__ Mt) {
  __shared__ __align__(16) uint16_t ws[64 * 64];   // 8 KB
  int bx = blockIdx.x;                       // (ly, b, h)
  int ly = bx >> 9, b = (bx >> 3) & 63, h = bx & 7;
  int t = threadIdx.x;                       // 64 threads = 1 wave
  float sf = sdfm[b * 64 + t] * 0.35355339059327373f;   // sqrt(1/8)
  for (int k = 0; k < 64; ++k) {
    float wv = qkv_w[((size_t)(ly * 64 + k)) * 1536 + h * 64 + t];
    ws[k * 64 + (((t >> 3) ^ (k & 7)) << 3) + (t & 7)] = f2b(wv * sf);
  }
  __syncthreads();
  int quad = t >> 4, c = t & 15;
  uint16_t* out = Mt + ((size_t)bx << 12);
  for (int it = 0; it < 4; ++it) {
    int ra = it * 16 + c, sa = ra & 7;
    bfrag8 a0 = *(const bfrag8*)(ws + ra * 64 + ((quad ^ sa) << 3));
    bfrag8 a1 = *(const bfrag8*)(ws + ra * 64 + (((quad + 4) ^ sa) << 3));
    for (int jt = 0; jt < 4; ++jt) {
      int rb = jt * 16 + c, sk = rb & 7;
      bfrag8 b0 = *(const bfrag8*)(ws + rb * 64 + ((quad ^ sk) << 3));
      bfrag8 b1 = *(const bfrag8*)(ws + rb * 64 + (((quad + 4) ^ sk) << 3));
      ffrag4 z = {0.f, 0.f, 0.f, 0.f};
      z = __builtin_amdgcn_mfma_f32_16x16x32_bf16(a0, b0, z, 0, 0, 0);
      z = __builtin_amdgcn_mfma_f32_16x16x32_bf16(a1, b1, z, 0, 0, 0);
      #pragma unroll
      for (int r = 0; r < 4; ++r)
        out[(it * 16 + quad * 4 + r) * 64 + jt * 16 + c] = f2b(z[r]);
    }
  }
}

// ---- attention core, M/G form: block per (sb,h), 4 waves ----
// S = (Xn·M_h)·Xn^T with A/B-frags from global (L1-hot); softmax; U = E·Xn with
// B-frags from LDS Xn^T (staged via identity-MFMA transpose, contiguous writes);
// store U/l into Og. k_proj then applies G = Wv·Wo. LDS = 38,912 B.
__global__ __launch_bounds__(256) void k_fattn(const uint16_t* __restrict__ Xn,
    const uint16_t* __restrict__ Mt,    // layer base [64 b][8 h][64][64]
    uint16_t* __restrict__ Og) {
  __shared__ __align__(16) uint16_t vt[64 * VTP];     // 29,696 B: Xn^T
  __shared__ __align__(16) uint16_t pwb[4][16 * PWP]; // 9,216 B: per-wave T/E
  int bh = blockIdx.x, sb = bh >> 3, h = bh & 7;
  int t = threadIdx.x, w = t >> 6, l = t & 63, quad = l >> 4, c = l & 15;
  const uint16_t* Xb = Xn + (size_t)sb * NTOK * ND;
  const uint16_t* Mh = Mt + (((size_t)(sb & 63) * 8 + h) << 12);
  uint16_t* pw = &pwb[w][0];

  // identity A-frags for the transpose MFMA: I[dt*16+c][k]
  bfrag8 idA[4], idB[4];
  #pragma unroll
  for (int dt = 0; dt < 4; ++dt) {
    int pos = dt * 16 + c;
    union { short s[8]; bfrag8 v; } u0, u1;
    #pragma unroll
    for (int e = 0; e < 8; ++e) {
      u0.s[e] = (pos < 32 && (pos >> 3) == quad && (pos & 7) == e) ? (short)0x3F80 : (short)0;
      u1.s[e] = (pos >= 32 && ((pos - 32) >> 3) == quad && (pos & 7) == e) ? (short)0x3F80 : (short)0;
    }
    idA[dt] = u0.v; idB[dt] = u1.v;
  }
  // stage vt = Xn^T via MFMA transpose: D[d][i] tiles, contiguous u16 writes
  for (int it2 = w; it2 < 15; it2 += 4) {
    int i0 = it2 * 16;
    int ric = i0 + c; if (ric > 225) ric = 225;
    bfrag8 x0 = *(const bfrag8*)(Xb + (size_t)ric * 64 + quad * 8);
    bfrag8 x1 = *(const bfrag8*)(Xb + (size_t)ric * 64 + 32 + quad * 8);
    #pragma unroll
    for (int dt = 0; dt < 4; ++dt) {
      ffrag4 z = {0.f, 0.f, 0.f, 0.f};
      z = __builtin_amdgcn_mfma_f32_16x16x32_bf16(idA[dt], x0, z, 0, 0, 0);
      z = __builtin_amdgcn_mfma_f32_16x16x32_bf16(idB[dt], x1, z, 0, 0, 0);
      if (i0 + c <= 231) {   // keep inside pitch; cols 226..231 are dups (E-masked)
        #pragma unroll
        for (int r = 0; r < 4; ++r)
          vt[(dt * 16 + quad * 4 + r) * VTP + i0 + c] = f2b(z[r]);
      }
    }
  }
  __syncthreads();

  for (int it = w; it < 15; it += 4) {
    int i0 = it * 16;
    int ric = i0 + c; if (ric > 225) ric = 225;
    bfrag8 aX0 = *(const bfrag8*)(Xb + (size_t)ric * 64 + quad * 8);
    bfrag8 aX1 = *(const bfrag8*)(Xb + (size_t)ric * 64 + 32 + quad * 8);
    // T = Xn_strip · M  (B = M rows, symmetric)
    ffrag4 tacc[4];
    #pragma unroll
    for (int dt = 0; dt < 4; ++dt) {
      bfrag8 b0 = *(const bfrag8*)(Mh + (dt * 16 + c) * 64 + quad * 8);
      bfrag8 b1 = *(const bfrag8*)(Mh + (dt * 16 + c) * 64 + 32 + quad * 8);
      ffrag4 z = {0.f, 0.f, 0.f, 0.f};
      z = __builtin_amdgcn_mfma_f32_16x16x32_bf16(aX0, b0, z, 0, 0, 0);
      z = __builtin_amdgcn_mfma_f32_16x16x32_bf16(aX1, b1, z, 0, 0, 0);
      tacc[dt] = z;
    }
    // T C-layout -> A-layout via pw
    #pragma unroll
    for (int dt = 0; dt < 4; ++dt)
      #pragma unroll
      for (int r = 0; r < 4; ++r)
        pw[(quad * 4 + r) * PWP + dt * 16 + c] = f2b(tacc[dt][r]);
    bfrag8 aT0 = *(const bfrag8*)(pw + c * PWP + quad * 8);
    bfrag8 aT1 = *(const bfrag8*)(pw + c * PWP + 32 + quad * 8);
    // S strip = T · Xn^T (B = global Xn rows, [j][k] layout)
    ffrag4 sacc[15];
    #pragma unroll
    for (int jt = 0; jt < 15; ++jt) {
      int rj = jt * 16 + c; if (rj > 225) rj = 225;
      bfrag8 b0 = *(const bfrag8*)(Xb + (size_t)rj * 64 + quad * 8);
      bfrag8 b1 = *(const bfrag8*)(Xb + (size_t)rj * 64 + 32 + quad * 8);
      ffrag4 z = {0.f, 0.f, 0.f, 0.f};
      z = __builtin_amdgcn_mfma_f32_16x16x32_bf16(aT0, b0, z, 0, 0, 0);
      z = __builtin_amdgcn_mfma_f32_16x16x32_bf16(aT1, b1, z, 0, 0, 0);
      sacc[jt] = z;
    }
    // softmax (raw E kept; 1/l at store)
    float rinv[4];
    #pragma unroll
    for (int r = 0; r < 4; ++r) {
      float m = -1e30f;
      #pragma unroll
      for (int jt = 0; jt < 15; ++jt) m = fmaxf(m, sacc[jt][r]);
      #pragma unroll
      for (int o = 8; o; o >>= 1) m = fmaxf(m, __shfl_xor(m, o));
      float s = 0.f;
      #pragma unroll
      for (int jt = 0; jt < 15; ++jt) {
        float p = __expf(sacc[jt][r] - m);
        if (jt == 14 && c >= 2) p = 0.f;   // j = 224+c >= 226 (dup rows) masked
        sacc[jt][r] = p;
        s += p;
      }
      #pragma unroll
      for (int o = 8; o; o >>= 1) s += __shfl_xor(s, o);
      rinv[r] = 1.f / s;
    }
    // U = E · Xn  (A: E via pw; B: vt rows)
    ffrag4 uacc[4];
    #pragma unroll
    for (int dt = 0; dt < 4; ++dt) uacc[dt] = (ffrag4){0.f, 0.f, 0.f, 0.f};
    #pragma unroll
    for (int jc = 0; jc < 8; ++jc) {
      if (jc == 7)
        *(uint64_t*)(pw + c * PWP + 16 + quad * 4) = 0ull;   // zero E cols 16..31
      #pragma unroll
      for (int r = 0; r < 4; ++r) {
        int row = quad * 4 + r;
        pw[row * PWP + c] = f2b(sacc[2 * jc][r]);
        if (jc < 7) pw[row * PWP + 16 + c] = f2b(sacc[2 * jc + 1][r]);
      }
      bfrag8 pa = *(const bfrag8*)(pw + c * PWP + quad * 8);
      #pragma unroll
      for (int dt = 0; dt < 4; ++dt) {
        bfrag8 vb;
        if (jc < 7)
          vb = *(const bfrag8*)(vt + (dt * 16 + c) * VTP + jc * 32 + quad * 8);
        else
          vb = *(const bfrag8*)(vt + (dt * 16 + c) * VTP + 224);  // E=0 beyond k-local 1
        uacc[dt] = __builtin_amdgcn_mfma_f32_16x16x32_bf16(pa, vb, uacc[dt], 0, 0, 0);
      }
    }
    // store normalized U into Og (k_proj applies G)
    #pragma unroll
    for (int dt = 0; dt < 4; ++dt) {
      #pragma unroll
      for (int r = 0; r < 4; ++r) {
        int i = i0 + quad * 4 + r;
        if (i < NTOK)
          Og[((size_t)sb * NTOK + i) * 512 + h * 64 + dt * 16 + c] =
              f2b(uacc[dt][r] * rinv[r]);
      }
    }
  }
}

// ---- MFMA out-projection (U·G) + residual + LN2 emission ----
__global__ __launch_bounds__(256) void k_proj(const uint16_t* __restrict__ Og,
    const uint16_t* __restrict__ Gp,    // [64][512] bf16 (this layer)
    const float* __restrict__ bo, float* __restrict__ X,
    const float* __restrict__ g2, const float* __restrict__ bb2,
    uint16_t* __restrict__ Xn2) {
  int t = threadIdx.x, w = t >> 6, l = t & 63;
  int quad = l >> 4, c = l & 15;
  int r0 = blockIdx.x * 64;
  const uint16_t* orow = Og + (size_t)(r0 + w * 16 + c) * 512 + quad * 8;
  bfrag8 a[16];
  #pragma unroll
  for (int kc = 0; kc < 16; ++kc) a[kc] = *(const bfrag8*)(orow + kc * 32);
  ffrag4 acc[4];
  #pragma unroll
  for (int jt = 0; jt < 4; ++jt) acc[jt] = (ffrag4){0.f, 0.f, 0.f, 0.f};
  #pragma unroll
  for (int kc = 0; kc < 16; ++kc) {
    #pragma unroll
    for (int jt = 0; jt < 4; ++jt) {
      bfrag8 b = *(const bfrag8*)(Gp + (size_t)(jt * 16 + c) * 512 + kc * 32 + quad * 8);
      acc[jt] = __builtin_amdgcn_mfma_f32_16x16x32_bf16(a[kc], b, acc[jt], 0, 0, 0);
    }
  }
  float xv[4][4];
  #pragma unroll
  for (int jt = 0; jt < 4; ++jt) {
    float bv = bo[jt * 16 + c];
    #pragma unroll
    for (int r = 0; r < 4; ++r) {
      int il = w * 16 + quad * 4 + r;
      size_t idx = (size_t)(r0 + il) * 64 + jt * 16 + c;
      float v = X[idx] + acc[jt][r] + bv;
      X[idx] = v;
      xv[jt][r] = v;
    }
  }
  #pragma unroll
  for (int r = 0; r < 4; ++r) {
    float s = xv[0][r] + xv[1][r] + xv[2][r] + xv[3][r];
    float q = xv[0][r]*xv[0][r] + xv[1][r]*xv[1][r] + xv[2][r]*xv[2][r] + xv[3][r]*xv[3][r];
    #pragma unroll
    for (int o = 8; o; o >>= 1) { s += __shfl_xor(s, o); q += __shfl_xor(q, o); }
    float m = s * (1.f / 64.f);
    float rs = rsqrtf(q * (1.f / 64.f) - m * m + 1e-5f);
    int il = w * 16 + quad * 4 + r;
    #pragma unroll
    for (int jt = 0; jt < 4; ++jt) {
      int n = jt * 16 + c;
      Xn2[(size_t)(r0 + il) * 64 + n] = f2b((xv[jt][r] - m) * rs * g2[n] + bb2[n]);
    }
  }
}

// ---- MFMA FF (A-frags from global Xn2) + residual + next-layer LN1 emission ----
__global__ __launch_bounds__(256) void k_ff(float* __restrict__ X,
    const uint16_t* __restrict__ Xn2,
    const uint16_t* __restrict__ W1t,   // [256][64] bf16
    const float* __restrict__ b1,
    const uint16_t* __restrict__ W2t,   // [64][256] bf16
    const float* __restrict__ b2,
    const float* __restrict__ gn, const float* __restrict__ bbn,
    uint16_t* __restrict__ XnOut) {
  __shared__ __align__(16) uint16_t ha[4][16 * 264];   // 33792 B, per-wave h-tile
  int t = threadIdx.x, w = t >> 6, l = t & 63;
  int quad = l >> 4, c = l & 15;
  int r0 = blockIdx.x * 64;
  const uint16_t* xrow = Xn2 + (size_t)(r0 + w * 16 + c) * 64;
  bfrag8 a0 = *(const bfrag8*)(xrow + quad * 8);
  bfrag8 a1 = *(const bfrag8*)(xrow + 32 + quad * 8);
  ffrag4 acc[16];
  #pragma unroll
  for (int jt = 0; jt < 16; ++jt) {
    bfrag8 b0  = *(const bfrag8*)(W1t + (size_t)(jt * 16 + c) * 64 + quad * 8);
    bfrag8 b1f = *(const bfrag8*)(W1t + (size_t)(jt * 16 + c) * 64 + 32 + quad * 8);
    ffrag4 z = {0.f, 0.f, 0.f, 0.f};
    z = __builtin_amdgcn_mfma_f32_16x16x32_bf16(a0, b0, z, 0, 0, 0);
    z = __builtin_amdgcn_mfma_f32_16x16x32_bf16(a1, b1f, z, 0, 0, 0);
    acc[jt] = z;
  }
  uint16_t* haw = &ha[w][0];
  #pragma unroll
  for (int jt = 0; jt < 16; ++jt) {
    float bv = b1[jt * 16 + c];
    #pragma unroll
    for (int r = 0; r < 4; ++r) {
      float z = acc[jt][r] + bv;
      float hg = 0.5f * z * (1.f + erff(z * 0.7071067811865476f));
      haw[(quad * 4 + r) * 264 + jt * 16 + c] = f2b(hg);
    }
  }
  __syncthreads();
  ffrag4 o2[4];
  #pragma unroll
  for (int jt = 0; jt < 4; ++jt) o2[jt] = (ffrag4){0.f, 0.f, 0.f, 0.f};
  #pragma unroll
  for (int kc = 0; kc < 8; ++kc) {
    bfrag8 pa = *(const bfrag8*)(haw + c * 264 + kc * 32 + quad * 8);
    #pragma unroll
    for (int jt = 0; jt < 4; ++jt) {
      bfrag8 vb = *(const bfrag8*)(W2t + (size_t)(jt * 16 + c) * 256 + kc * 32 + quad * 8);
      o2[jt] = __builtin_amdgcn_mfma_f32_16x16x32_bf16(pa, vb, o2[jt], 0, 0, 0);
    }
  }
  float xv[4][4];
  #pragma unroll
  for (int jt = 0; jt < 4; ++jt) {
    float bv = b2[jt * 16 + c];
    #pragma unroll
    for (int r = 0; r < 4; ++r) {
      int il = w * 16 + quad * 4 + r;
      size_t idx = (size_t)(r0 + il) * 64 + jt * 16 + c;
      float v = X[idx] + o2[jt][r] + bv;
      X[idx] = v;
      xv[jt][r] = v;
    }
  }
  #pragma unroll
  for (int r = 0; r < 4; ++r) {
    float s = xv[0][r] + xv[1][r] + xv[2][r] + xv[3][r];
    float q = xv[0][r]*xv[0][r] + xv[1][r]*xv[1][r] + xv[2][r]*xv[2][r] + xv[3][r]*xv[3][r];
    #pragma unroll
    for (int o = 8; o; o >>= 1) { s += __shfl_xor(s, o); q += __shfl_xor(q, o); }
    float m = s * (1.f / 64.f);
    float rs = rsqrtf(q * (1.f / 64.f) - m * m + 1e-5f);
    int il = w * 16 + quad * 4 + r;
    #pragma unroll
    for (int jt = 0; jt < 4; ++jt) {
      int n = jt * 16 + c;
      XnOut[(size_t)(r0 + il) * 64 + n] = f2b((xv[jt][r] - m) * rs * gn[n] + bbn[n]);
    }
  }
}

// ---- swap cls tokens between streams; refresh Xn (LN1 layer0) for those rows ----
__global__ void k_xchg(float* __restrict__ X, uint16_t* __restrict__ Xn,
                       const float* __restrict__ g, const float* __restrict__ bb) {
  int b = blockIdx.x, d = threadIdx.x;   // 64 blocks x 64 threads (1 wave)
  size_t i0 = (size_t)(b * NTOK) * ND + d;
  size_t i1 = (size_t)((64 + b) * NTOK) * ND + d;
  float a = X[i0], cc = X[i1];
  X[i0] = cc; X[i1] = a;
  float s0 = cc, q0 = cc * cc, s1 = a, q1 = a * a;
  #pragma unroll
  for (int o = 32; o; o >>= 1) {
    s0 += __shfl_xor(s0, o); q0 += __shfl_xor(q0, o);
    s1 += __shfl_xor(s1, o); q1 += __shfl_xor(q1, o);
  }
  float m0 = s0 * (1.f / 64.f), rs0 = rsqrtf(q0 * (1.f / 64.f) - m0 * m0 + 1e-5f);
  float m1 = s1 * (1.f / 64.f), rs1 = rsqrtf(q1 * (1.f / 64.f) - m1 * m1 + 1e-5f);
  Xn[i0] = f2b((cc - m0) * rs0 * g[d] + bb[d]);
  Xn[i1] = f2b((a - m1) * rs1 * g[d] + bb[d]);
}

// ---- final: out = h_cls + l_cls ----
__global__ void k_out(const float* __restrict__ X, float* __restrict__ out) {
  int i = blockIdx.x * 64 + threadIdx.x;
  int b = i >> 6, d = i & 63;
  out[i] = X[(size_t)b * NTOK * ND + d] + X[(size_t)(64 + b) * NTOK * ND + d];
}

extern "C" void kernel_launch(void* const* d_in, const int* in_sizes, int n_in,
                              void* d_out, int out_size, void* d_ws, size_t ws_size,
                              hipStream_t stream) {
  const float* hsi   = (const float*)d_in[0];
  const float* lidar = (const float*)d_in[1];
  const float* cls_h = (const float*)d_in[2];
  const float* cls_l = (const float*)d_in[3];
  const float* pos_h = (const float*)d_in[4];
  const float* pos_l = (const float*)d_in[5];
  const float* fmg_w = (const float*)d_in[6];
  const float* ln1_g = (const float*)d_in[7];
  const float* ln1_b = (const float*)d_in[8];
  const float* qkv_w = (const float*)d_in[9];
  const float* out_w = (const float*)d_in[10];
  const float* out_b = (const float*)d_in[11];
  const float* ln2_g = (const float*)d_in[12];
  const float* ln2_b = (const float*)d_in[13];
  const float* ff_w1 = (const float*)d_in[14];
  const float* ff_b1 = (const float*)d_in[15];
  const float* ff_w2 = (const float*)d_in[16];
  const float* ff_b2 = (const float*)d_in[17];

  char* ws = (char*)d_ws;
  float*    X    = (float*)ws;                       // 7,405,568 B
  float*    sdfm = (float*)(ws + 7405568);           // 16,384 B
  uint16_t* Xn   = (uint16_t*)(ws + 7421952);        // 3,702,784 B
  uint16_t* Xn2  = (uint16_t*)(ws + 11124736);       // 3,702,784 B
  uint16_t* Og   = (uint16_t*)(ws + 14827520);       // 29,622,272 B
  uint16_t* Mt   = (uint16_t*)(ws + 44449792);       // 16,777,216 B
  uint16_t* Gp   = (uint16_t*)(ws + 61227008);       // 262,144 B
  uint16_t* W1   = (uint16_t*)(ws + 61489152);       // 131,072 B
  uint16_t* W2   = (uint16_t*)(ws + 61620224);       // 131,072 B -> end 61,751,296

  k_wconv2<<<512, 256, 0, stream>>>(ff_w1, ff_w2, W1, W2);
  k_gconv<<<512, 256, 0, stream>>>(qkv_w, out_w, Gp);
  k_dfm<<<NB, 128, 0, stream>>>(hsi, lidar, fmg_w, sdfm);
  k_mconv<<<2048, 64, 0, stream>>>(qkv_w, sdfm, Mt);
  k_build<<<NROWS, 64, 0, stream>>>(hsi, cls_h, cls_l, pos_h, pos_l,
                                    ln1_g, ln1_b, X, Xn);
  for (int pass = 0; pass < 2; ++pass) {
    for (int ly = 0; ly < 4; ++ly) {
      int nx = (ly + 1) & 3;   // next layer's LN1 params (harmless on final layer)
      k_fattn<<<NSB * NH, 256, 0, stream>>>(Xn, Mt + (size_t)ly * 2097152, Og);
      k_proj<<<452, 256, 0, stream>>>(Og, Gp + (size_t)ly * 32768, out_b + ly * ND,
                                      X, ln2_g + ly * ND, ln2_b + ly * ND, Xn2);
      k_ff<<<452, 256, 0, stream>>>(X, Xn2,
                                    W1 + (size_t)ly * 16384, ff_b1 + ly * 256,
                                    W2 + (size_t)ly * 16384, ff_b2 + ly * ND,
                                    ln1_g + nx * ND, ln1_b + nx * ND, Xn);
    }
    if (pass == 0) k_xchg<<<64, 64, 0, stream>>>(X, Xn, ln1_g, ln1_b);
  }
  k_out<<<64, 64, 0, stream>>>(X, (float*)d_out);
}